// Round 10
// baseline (162.517 us; speedup 1.0000x reference)
//
#include <hip/hip_runtime.h>
#include <stdint.h>

// OutliersQLinearUnstruct: out[b][o] = sum_i x[b][i]*w_eff[o][i] + bias[o]
//   w_eff = mask ? w : scale_o * sign(w - mean_o) (sign of centered masked row)
// Identity: at non-outlier positions sign(wz-mean)=sign(w-mean) (raw w), so
//   out = scale_o * sum_i sgn(w_i-mean_o) x_i
//       + sum_{outlier i} (w_i - scale_o*sgn(w_i-mean_o)) x_i   [sparse]
// R10: traffic-minimal pipeline.
//   K0 xprep: xbf [B][IC] bf16 (MFMA A) + xT [IC][B] bf16 (sparse path).
//   K1 fuse2: wave/row: stats -> signs 1-bit (u64[OC][64], lane-strided),
//             scale[OC], sparse corr list (idx16|bf16corr, CAP=512/row).
//             Reads 360MB, writes ~15MB (was 88MB weff).
//   K2 binary MFMA GEMM: expand sign bits -> +-1 bf16 frags, scale in epilogue.
//   K2b sparse correction GEMV -> part slot 8.
//   K3 reduce 9 slots + bias.

#define OC 11008
#define IC 4096
#define BATCH 32
#define SKM 8
#define SKF 4
#define CAP 512

typedef __attribute__((ext_vector_type(8))) short short8;
typedef __attribute__((ext_vector_type(4))) float floatx4;
typedef __attribute__((ext_vector_type(4))) unsigned int uintx4;

static __device__ __forceinline__ unsigned short f2bf(float f) {
  uint32_t u = __builtin_bit_cast(uint32_t, f);
  uint32_t r = (u + 0x7fffu + ((u >> 16) & 1u)) >> 16;
  return (unsigned short)r;
}
static __device__ __forceinline__ float bf2f(unsigned short h) {
  uint32_t u = ((uint32_t)h) << 16;
  return __builtin_bit_cast(float, u);
}

// ---------------- K0: x prep ----------------
// blocks 0..63: xT (i = blk*64 + t/4, b0=(t&3)*8). blocks 64..95: xbf row.
__global__ __launch_bounds__(256) void xprep_kernel(
    const float* __restrict__ x, unsigned short* __restrict__ xbf,
    unsigned short* __restrict__ xT) {
  const int blk = blockIdx.x;
  const int t = threadIdx.x;
  if (blk < 64) {
    const int i = blk * 64 + (t >> 2);
    const int b0 = (t & 3) * 8;
    unsigned short tmp[8];
#pragma unroll
    for (int j = 0; j < 8; ++j) tmp[j] = f2bf(x[(size_t)(b0 + j) * IC + i]);
    *reinterpret_cast<short8*>(xT + (size_t)i * BATCH + b0) =
        *reinterpret_cast<short8*>(tmp);
  } else {
    const int b = blk - 64;
    const float* xr = x + (size_t)b * IC;
    unsigned short* xo = xbf + (size_t)b * IC;
#pragma unroll
    for (int q = 0; q < 4; ++q) {
      const int i = (q << 10) + (t << 2);
      const float4 v = *reinterpret_cast<const float4*>(xr + i);
      ushort4 u;
      u.x = f2bf(v.x); u.y = f2bf(v.y); u.z = f2bf(v.z); u.w = f2bf(v.w);
      *reinterpret_cast<ushort4*>(xo + i) = u;
    }
  }
}

// ---------------- K1: stats + sign-pack + sparse extract ----------------
// wave per row (4 rows/block). Lane owns elems i = q*256 + lane*4 + e.
// signs[row][lane] bit (q*4+e) = (w < mean).  corr list per row, CAP slots.
__global__ __launch_bounds__(256) void fuse2_kernel(
    const float* __restrict__ w, const int* __restrict__ mask,
    unsigned long long* __restrict__ signs, float* __restrict__ scaleArr,
    int* __restrict__ countArr, uint32_t* __restrict__ corrArr) {
  const int blk = blockIdx.x;
  const int t = threadIdx.x;
  const int lane = t & 63;
  const int wvid = t >> 6;
  const int row = blk * 4 + wvid;

  const float* wr = w + (size_t)row * IC;
  const int* mr = mask + (size_t)row * IC;

  float4 wv[16];
  unsigned long long mb = 0;
  float s1 = 0.f, s2 = 0.f;
#pragma unroll
  for (int q = 0; q < 16; ++q) {
    const int i = (q << 8) + (lane << 2);
    wv[q] = *reinterpret_cast<const float4*>(wr + i);
    const int4 mv = *reinterpret_cast<const int4*>(mr + i);
    const uint32_t nb = (uint32_t)(mv.x != 0) | ((uint32_t)(mv.y != 0) << 1) |
                        ((uint32_t)(mv.z != 0) << 2) |
                        ((uint32_t)(mv.w != 0) << 3);
    mb |= (unsigned long long)nb << (q * 4);
    const float z0 = (nb & 1u) ? 0.f : wv[q].x;
    const float z1 = (nb & 2u) ? 0.f : wv[q].y;
    const float z2 = (nb & 4u) ? 0.f : wv[q].z;
    const float z3 = (nb & 8u) ? 0.f : wv[q].w;
    s1 += z0 + z1 + z2 + z3;
    s2 += fabsf(z0) + fabsf(z1) + fabsf(z2) + fabsf(z3);
  }

#pragma unroll
  for (int off = 1; off < 64; off <<= 1) {
    s1 += __shfl_xor(s1, off);
    s2 += __shfl_xor(s2, off);
  }
  const float mean = s1 * (1.0f / IC);
  const float scale = s2 * (1.0f / IC);
  if (lane == 0) scaleArr[row] = scale;

  // sign pack (bit=1 => sigma=-1)
  unsigned long long sb = 0;
#pragma unroll
  for (int q = 0; q < 16; ++q) {
    sb |= (unsigned long long)(wv[q].x < mean) << (q * 4 + 0);
    sb |= (unsigned long long)(wv[q].y < mean) << (q * 4 + 1);
    sb |= (unsigned long long)(wv[q].z < mean) << (q * 4 + 2);
    sb |= (unsigned long long)(wv[q].w < mean) << (q * 4 + 3);
  }
  signs[(size_t)row * 64 + lane] = sb;

  // sparse extraction: per-lane count + wave prefix scan
  int cnt = __popcll(mb);
  int pref = cnt;
#pragma unroll
  for (int d = 1; d < 64; d <<= 1) {
    int v = __shfl_up(pref, d);
    if (lane >= d) pref += v;
  }
  if (lane == 63) countArr[row] = (pref < CAP) ? pref : CAP;
  int pos = pref - cnt;
  unsigned long long mm = mb;
  while (mm) {
    const int b = __ffsll(mm) - 1;
    mm &= mm - 1;
    const int q = b >> 2, e = b & 3;
    const int idx = (q << 8) + (lane << 2) + e;
    const float val = wr[idx];  // L1/L2-hot reload (avoids runtime reg index)
    const float sg = (val < mean) ? -scale : scale;
    const float corr = val - sg;
    if (pos < CAP)
      corrArr[(size_t)row * CAP + pos] =
          ((uint32_t)idx << 16) | (uint32_t)f2bf(corr);
    ++pos;
  }
}

// ---------------- K2: binary MFMA GEMM (signs -> +-1 bf16) ----------------
__global__ __launch_bounds__(256) void mfma_kernel(
    const unsigned long long* __restrict__ signs,
    const float* __restrict__ scaleArr, const unsigned short* __restrict__ xbf,
    float* __restrict__ part) {
  const int bx = blockIdx.x;
  const int tile = bx >> 3;
  const int sk = bx & 7;
  const int t = threadIdx.x;
  const int wv = t >> 6;
  const int l = t & 63;
  const int l15 = l & 15, l4 = l >> 4;

  const int o = tile * 64 + wv * 16 + l15;
  const int k0 = sk * (IC / SKM) + l4 * 8;

  const unsigned long long* sgp = signs + (size_t)o * 64;
  const unsigned short* ap0 = xbf + (size_t)l15 * IC + k0;
  const unsigned short* ap1 = xbf + (size_t)(16 + l15) * IC + k0;
  const float scl = scaleArr[o];

  floatx4 acc0 = {0.f, 0.f, 0.f, 0.f};
  floatx4 acc1 = {0.f, 0.f, 0.f, 0.f};
#pragma unroll
  for (int kk = 0; kk < 16; ++kk) {
    const int k = k0 + kk * 32;
    const int l_src = (k & 255) >> 2;
    const int sh = (k >> 8) * 4;
    const unsigned long long s0 = sgp[l_src];
    const unsigned long long s1v = sgp[l_src + 1];
    const uint32_t bits8 = ((uint32_t)(s0 >> sh) & 0xFu) |
                           (((uint32_t)(s1v >> sh) & 0xFu) << 4);
    uintx4 pr;
#pragma unroll
    for (int p = 0; p < 4; ++p) {
      pr[p] = (((bits8 >> (2 * p)) & 1u) ? 0xBF80u : 0x3F80u) |
              (((bits8 >> (2 * p + 1)) & 1u) ? 0xBF800000u : 0x3F800000u);
    }
    const short8 bf = __builtin_bit_cast(short8, pr);
    const short8 a0 = *reinterpret_cast<const short8*>(ap0 + kk * 32);
    const short8 a1 = *reinterpret_cast<const short8*>(ap1 + kk * 32);
    acc0 = __builtin_amdgcn_mfma_f32_16x16x32_bf16(a0, bf, acc0, 0, 0, 0);
    acc1 = __builtin_amdgcn_mfma_f32_16x16x32_bf16(a1, bf, acc1, 0, 0, 0);
  }

  float* pb = part + (size_t)sk * (BATCH * OC);
#pragma unroll
  for (int r = 0; r < 4; ++r) {
    const int b0 = l4 * 4 + r;
    pb[(size_t)b0 * OC + o] = acc0[r] * scl;
    pb[(size_t)(b0 + 16) * OC + o] = acc1[r] * scl;
  }
}

// ---------------- K2b: sparse outlier correction -> part slot SKM ----------
__global__ __launch_bounds__(256) void sparse_kernel(
    const uint32_t* __restrict__ corrArr, const int* __restrict__ countArr,
    const unsigned short* __restrict__ xT, float* __restrict__ part) {
  __shared__ float lds[4][64][33];
  const int t = threadIdx.x;
  const int lane = t & 63;
  const int wvid = t >> 6;
  const int row = blockIdx.x * 4 + wvid;

  const int cnt = countArr[row];
  float acc[32];
#pragma unroll
  for (int b = 0; b < 32; ++b) acc[b] = 0.f;

  for (int j = lane; j < cnt; j += 64) {
    const uint32_t p = corrArr[(size_t)row * CAP + j];
    const int idx = p >> 16;
    const float cv = bf2f((unsigned short)(p & 0xFFFFu));
    const unsigned short* xr = xT + (size_t)idx * BATCH;
    const short8 h0 = *reinterpret_cast<const short8*>(xr);
    const short8 h1 = *reinterpret_cast<const short8*>(xr + 8);
    const short8 h2 = *reinterpret_cast<const short8*>(xr + 16);
    const short8 h3 = *reinterpret_cast<const short8*>(xr + 24);
#pragma unroll
    for (int e = 0; e < 8; ++e) {
      acc[e] += cv * bf2f((unsigned short)h0[e]);
      acc[8 + e] += cv * bf2f((unsigned short)h1[e]);
      acc[16 + e] += cv * bf2f((unsigned short)h2[e]);
      acc[24 + e] += cv * bf2f((unsigned short)h3[e]);
    }
  }

#pragma unroll
  for (int b = 0; b < 32; ++b) lds[wvid][lane][b] = acc[b];
  // wave-synchronous LDS (same wave writes then reads; lockstep + lgkmcnt)
  if (lane < 32) {
    float s = 0.f;
    for (int l2 = 0; l2 < 64; ++l2) s += lds[wvid][l2][lane];
    part[(size_t)SKM * (BATCH * OC) + (size_t)lane * OC + row] = s;
  }
}

__global__ __launch_bounds__(256) void reduce_kernel(
    const float* __restrict__ part, const float* __restrict__ bias,
    float* __restrict__ out, int nsk) {
  const int idx = blockIdx.x * 256 + threadIdx.x;
  if (idx < BATCH * OC) {
    const int o = idx % OC;
    float v = bias[o];
    for (int sk = 0; sk < nsk; ++sk) v += part[(size_t)sk * (BATCH * OC) + idx];
    out[idx] = v;
  }
}

// ---------------- Fallback (f32 VALU path, known-correct) ----------------
__global__ __launch_bounds__(256) void stats_kernel_fb(
    const int* __restrict__ mask, const float* __restrict__ w,
    float2* __restrict__ stats) {
  const int o = blockIdx.x;
  const int t = threadIdx.x;
  const float* wr = w + (size_t)o * IC;
  const int* mr = mask + (size_t)o * IC;
  float s1 = 0.f, s2 = 0.f;
#pragma unroll
  for (int q = 0; q < 4; ++q) {
    const int i = (q << 10) + (t << 2);
    const float4 wv = *reinterpret_cast<const float4*>(wr + i);
    const int4 mv = *reinterpret_cast<const int4*>(mr + i);
    const float z0 = mv.x ? 0.f : wv.x, z1 = mv.y ? 0.f : wv.y;
    const float z2 = mv.z ? 0.f : wv.z, z3 = mv.w ? 0.f : wv.w;
    s1 += z0 + z1 + z2 + z3;
    s2 += fabsf(z0) + fabsf(z1) + fabsf(z2) + fabsf(z3);
  }
#pragma unroll
  for (int off = 32; off > 0; off >>= 1) {
    s1 += __shfl_down(s1, off);
    s2 += __shfl_down(s2, off);
  }
  __shared__ float r1[4], r2[4];
  if ((t & 63) == 0) { r1[t >> 6] = s1; r2[t >> 6] = s2; }
  __syncthreads();
  if (t == 0)
    stats[o] = make_float2((r1[0] + r1[1] + r1[2] + r1[3]) * (1.0f / IC),
                           (r2[0] + r2[1] + r2[2] + r2[3]) * (1.0f / IC));
}

__global__ __launch_bounds__(256) void gemv_kernel_fb(
    const float* __restrict__ x, const float* __restrict__ w,
    const int* __restrict__ mask, const float2* __restrict__ stats,
    float* __restrict__ part) {
  const int bx = blockIdx.x;
  const int tile = bx >> 2;
  const int sk = bx & 3;
  const int t = threadIdx.x;
  const int wvid = t >> 6;
  const int lane = t & 63;
  const int il = lane & 15;
  const int bg = lane >> 4;
  const int row0 = tile * 32 + wvid * 8;
  const int i0 = sk * (IC / SKF);
  const float* wr0 = w + (size_t)row0 * IC;
  const int* mk0 = mask + (size_t)row0 * IC;
  const float* xb = x + (size_t)(bg * 8) * IC;

  float2 stv[8];
#pragma unroll
  for (int r = 0; r < 8; ++r) stv[r] = stats[row0 + r];
  float acc[8][8];
#pragma unroll
  for (int r = 0; r < 8; ++r)
#pragma unroll
    for (int j = 0; j < 8; ++j) acc[r][j] = 0.f;

  for (int s_ = 0; s_ < (IC / SKF) / 64; ++s_) {
    const int i = i0 + (s_ << 6) + (il << 2);
    float4 wf[8];
#pragma unroll
    for (int r = 0; r < 8; ++r) {
      wf[r] = *reinterpret_cast<const float4*>(wr0 + (size_t)r * IC + i);
      const int4 mv = *reinterpret_cast<const int4*>(mk0 + (size_t)r * IC + i);
      const float m = stv[r].x, sc = stv[r].y;
      wf[r].x = mv.x ? wf[r].x : copysignf(sc, wf[r].x - m);
      wf[r].y = mv.y ? wf[r].y : copysignf(sc, wf[r].y - m);
      wf[r].z = mv.z ? wf[r].z : copysignf(sc, wf[r].z - m);
      wf[r].w = mv.w ? wf[r].w : copysignf(sc, wf[r].w - m);
    }
#pragma unroll
    for (int j = 0; j < 8; ++j) {
      const float4 xv = *reinterpret_cast<const float4*>(xb + (size_t)j * IC + i);
#pragma unroll
      for (int r = 0; r < 8; ++r)
        acc[r][j] += wf[r].x * xv.x + wf[r].y * xv.y + wf[r].z * xv.z +
                     wf[r].w * xv.w;
    }
  }
#pragma unroll
  for (int off = 8; off >= 1; off >>= 1)
#pragma unroll
    for (int r = 0; r < 8; ++r)
#pragma unroll
      for (int j = 0; j < 8; ++j) acc[r][j] += __shfl_xor(acc[r][j], off);
  if (il == 0)
#pragma unroll
    for (int r = 0; r < 8; ++r)
#pragma unroll
      for (int j = 0; j < 8; ++j)
        part[(size_t)sk * (BATCH * OC) + (size_t)(bg * 8 + j) * OC +
             (row0 + r)] = acc[r][j];
}

// ---------------- launch ----------------
extern "C" void kernel_launch(void* const* d_in, const int* in_sizes, int n_in,
                              void* d_out, int out_size, void* d_ws,
                              size_t ws_size, hipStream_t stream) {
  const float* x = (const float*)d_in[0];
  const float* w = (const float*)d_in[1];
  const float* bias = (const float*)d_in[2];
  const int* mask = (const int*)d_in[3];
  float* out = (float*)d_out;

  const size_t scale_b = (size_t)OC * 4;
  const size_t count_b = (size_t)OC * 4;
  const size_t signs_b = (size_t)OC * 64 * 8;                 // 5.6 MB
  const size_t corr_b = (size_t)OC * CAP * 4;                 // 22.5 MB
  const size_t xbf_b = (size_t)BATCH * IC * 2;                // 256 KB
  const size_t xT_b = (size_t)IC * BATCH * 2;                 // 256 KB
  const size_t part_b = (size_t)(SKM + 1) * BATCH * OC * 4;   // 12.7 MB
  const size_t need = scale_b + count_b + signs_b + corr_b + xbf_b + xT_b + part_b;

  if (ws_size >= need) {
    char* p = (char*)d_ws;
    float* scaleArr = (float*)p;                 p += scale_b;
    int* countArr = (int*)p;                     p += count_b;
    unsigned long long* signs = (unsigned long long*)p; p += signs_b;
    uint32_t* corrArr = (uint32_t*)p;            p += corr_b;
    unsigned short* xbf = (unsigned short*)p;    p += xbf_b;
    unsigned short* xT = (unsigned short*)p;     p += xT_b;
    float* part = (float*)p;

    xprep_kernel<<<96, 256, 0, stream>>>(x, xbf, xT);
    fuse2_kernel<<<OC / 4, 256, 0, stream>>>(w, mask, signs, scaleArr,
                                             countArr, corrArr);
    mfma_kernel<<<(OC / 64) * SKM, 256, 0, stream>>>(signs, scaleArr, xbf,
                                                     part);
    sparse_kernel<<<OC / 4, 256, 0, stream>>>(corrArr, countArr, xT, part);
    reduce_kernel<<<(BATCH * OC + 255) / 256, 256, 0, stream>>>(part, bias, out,
                                                                SKM + 1);
  } else {
    float2* stats = (float2*)d_ws;
    float* part = (float*)((char*)d_ws + (size_t)OC * sizeof(float2));
    stats_kernel_fb<<<OC, 256, 0, stream>>>(mask, w, stats);
    gemv_kernel_fb<<<(OC / 32) * SKF, 256, 0, stream>>>(x, w, mask, stats, part);
    reduce_kernel<<<(BATCH * OC + 255) / 256, 256, 0, stream>>>(part, bias, out,
                                                                SKF);
  }
}

// Round 11
// 118.491 us; speedup vs baseline: 1.3716x; 1.3716x over previous
//
#include <hip/hip_runtime.h>
#include <stdint.h>

// OutliersQLinearUnstruct: out[b][o] = sum_i x[b][i]*w_eff[o][i] + bias[o]
//   w_eff = mask ? w : scale_o * sign(w - mean_o)
//   mean_o = mean(wz_row), scale_o = mean(|wz_row|), wz = mask ? 0 : w
// OC=11008, IC=4096, B=32. x/w/bias f32; mask int32 (nonzero = outlier).
//
// R11 = R9 (copy-shaped fuse: 1024 thr/block, one row/block, one float4 +
//       one int4 per thread, single LDS reduce) + NONTEMPORAL loads on BOTH
//       w and mask (each read exactly once per call; bypass L2/L3 fill path,
//       which steady-state counters implicate as the ~3.8 TB/s binder).
//       weff store stays cacheable (mfma re-reads it from L3).
//       K2 MFMA bf16 GEMM (split-K=8) and K3 reduce unchanged from R9.

#define OC 11008
#define IC 4096
#define BATCH 32
#define SKM 8              // split-K for MFMA gemm
#define SKF 4              // split-K for fallback gemv

typedef __attribute__((ext_vector_type(8))) short short8;
typedef __attribute__((ext_vector_type(4))) float floatx4;
typedef __attribute__((ext_vector_type(4))) int intx4;

static __device__ __forceinline__ unsigned short f2bf(float f) {
  uint32_t u = __builtin_bit_cast(uint32_t, f);
  uint32_t r = (u + 0x7fffu + ((u >> 16) & 1u)) >> 16;
  return (unsigned short)r;
}

// ---------------- K1: fused stats + transform + bf16 stores ----------------
// blocks 0..31: x-cast (one b-row each, 1024 thr = 1 float4/thread).
// blocks 32..32+OC-1: one w-row each.
__global__ __launch_bounds__(1024) void fuse_kernel(
    const float* __restrict__ w, const int* __restrict__ mask,
    const float* __restrict__ x, unsigned short* __restrict__ weff,
    unsigned short* __restrict__ xbf) {
  const int blk = blockIdx.x;
  const int t = threadIdx.x;
  const int i = t << 2;  // element offset of this thread's float4

  if (blk < BATCH) {  // x cast: row b = blk
    const float* xr = x + (size_t)blk * IC;
    unsigned short* xo = xbf + (size_t)blk * IC;
    const float4 v = *reinterpret_cast<const float4*>(xr + i);
    ushort4 u;
    u.x = f2bf(v.x); u.y = f2bf(v.y); u.z = f2bf(v.z); u.w = f2bf(v.w);
    *reinterpret_cast<ushort4*>(xo + i) = u;
    return;
  }

  const int row = blk - BATCH;
  const float* wr = w + (size_t)row * IC;
  const int* mr = mask + (size_t)row * IC;

  // One float4 + one int4 per thread — both NONTEMPORAL (single-use data).
  const floatx4 wv =
      __builtin_nontemporal_load(reinterpret_cast<const floatx4*>(wr + i));
  const intx4 mv =
      __builtin_nontemporal_load(reinterpret_cast<const intx4*>(mr + i));
  const uint32_t nb = (uint32_t)(mv.x != 0) | ((uint32_t)(mv.y != 0) << 1) |
                      ((uint32_t)(mv.z != 0) << 2) |
                      ((uint32_t)(mv.w != 0) << 3);
  const float z0 = (nb & 1u) ? 0.f : wv.x;
  const float z1 = (nb & 2u) ? 0.f : wv.y;
  const float z2 = (nb & 4u) ? 0.f : wv.z;
  const float z3 = (nb & 8u) ? 0.f : wv.w;
  float s1 = z0 + z1 + z2 + z3;
  float s2 = fabsf(z0) + fabsf(z1) + fabsf(z2) + fabsf(z3);

  // Wave butterfly (all lanes get wave sum), then one LDS round.
#pragma unroll
  for (int off = 1; off < 64; off <<= 1) {
    s1 += __shfl_xor(s1, off);
    s2 += __shfl_xor(s2, off);
  }
  __shared__ float red[16][2];
  const int wvid = t >> 6;
  if ((t & 63) == 0) { red[wvid][0] = s1; red[wvid][1] = s2; }
  __syncthreads();
  float a = 0.f, b = 0.f;
#pragma unroll
  for (int k = 0; k < 16; ++k) { a += red[k][0]; b += red[k][1]; }
  const float mean = a * (1.0f / IC);
  const float scale = b * (1.0f / IC);

  // Transform + store from still-live registers (weff stays cacheable:
  // the MFMA GEMM re-reads it from L3 immediately after).
  float v0 = (nb & 1u) ? wv.x : copysignf(scale, wv.x - mean);
  float v1 = (nb & 2u) ? wv.y : copysignf(scale, wv.y - mean);
  float v2 = (nb & 4u) ? wv.z : copysignf(scale, wv.z - mean);
  float v3 = (nb & 8u) ? wv.w : copysignf(scale, wv.w - mean);
  ushort4 u;
  u.x = f2bf(v0); u.y = f2bf(v1); u.z = f2bf(v2); u.w = f2bf(v3);
  *reinterpret_cast<ushort4*>(weff + (size_t)row * IC + i) = u;
}

// ---------------- K2: bf16 MFMA GEMM, split-K ----------------
// block = 4 waves; wave wv owns cols [tile*64 + wv*16, +16), K-chunk sk*512.
// D: col = lane&15, row(b) = (lane>>4)*4 + reg  [m89 layout].
__global__ __launch_bounds__(256) void mfma_kernel(
    const unsigned short* __restrict__ weff,
    const unsigned short* __restrict__ xbf, float* __restrict__ part) {
  const int bx = blockIdx.x;
  const int tile = bx >> 3;
  const int sk = bx & 7;
  const int t = threadIdx.x;
  const int wv = t >> 6;
  const int l = t & 63;
  const int l15 = l & 15, l4 = l >> 4;

  const int o = tile * 64 + wv * 16 + l15;
  const int k0 = sk * (IC / SKM) + l4 * 8;

  const unsigned short* bp = weff + (size_t)o * IC + k0;
  const unsigned short* ap0 = xbf + (size_t)l15 * IC + k0;
  const unsigned short* ap1 = xbf + (size_t)(16 + l15) * IC + k0;

  floatx4 acc0 = {0.f, 0.f, 0.f, 0.f};
  floatx4 acc1 = {0.f, 0.f, 0.f, 0.f};
#pragma unroll 4
  for (int kk = 0; kk < (IC / SKM) / 32; ++kk) {  // 16 iters
    const short8 bf = *reinterpret_cast<const short8*>(bp + kk * 32);
    const short8 a0 = *reinterpret_cast<const short8*>(ap0 + kk * 32);
    const short8 a1 = *reinterpret_cast<const short8*>(ap1 + kk * 32);
    acc0 = __builtin_amdgcn_mfma_f32_16x16x32_bf16(a0, bf, acc0, 0, 0, 0);
    acc1 = __builtin_amdgcn_mfma_f32_16x16x32_bf16(a1, bf, acc1, 0, 0, 0);
  }

  float* pb = part + (size_t)sk * (BATCH * OC);
#pragma unroll
  for (int r = 0; r < 4; ++r) {
    const int b0 = l4 * 4 + r;
    pb[(size_t)b0 * OC + o] = acc0[r];
    pb[(size_t)(b0 + 16) * OC + o] = acc1[r];
  }
}

__global__ __launch_bounds__(256) void reduce_kernel(
    const float* __restrict__ part, const float* __restrict__ bias,
    float* __restrict__ out, int nsk) {
  const int idx = blockIdx.x * 256 + threadIdx.x;
  if (idx < BATCH * OC) {
    const int o = idx % OC;
    float v = bias[o];
    for (int sk = 0; sk < nsk; ++sk) v += part[(size_t)sk * (BATCH * OC) + idx];
    out[idx] = v;
  }
}

// ---------------- Fallback (f32 VALU path, known-correct) ----------------
__global__ __launch_bounds__(256) void stats_kernel_fb(
    const int* __restrict__ mask, const float* __restrict__ w,
    float2* __restrict__ stats) {
  const int o = blockIdx.x;
  const int t = threadIdx.x;
  const float* wr = w + (size_t)o * IC;
  const int* mr = mask + (size_t)o * IC;
  float s1 = 0.f, s2 = 0.f;
#pragma unroll
  for (int q = 0; q < 4; ++q) {
    const int i = (q << 10) + (t << 2);
    const float4 wv = *reinterpret_cast<const float4*>(wr + i);
    const int4 mv = *reinterpret_cast<const int4*>(mr + i);
    const float z0 = mv.x ? 0.f : wv.x, z1 = mv.y ? 0.f : wv.y;
    const float z2 = mv.z ? 0.f : wv.z, z3 = mv.w ? 0.f : wv.w;
    s1 += z0 + z1 + z2 + z3;
    s2 += fabsf(z0) + fabsf(z1) + fabsf(z2) + fabsf(z3);
  }
#pragma unroll
  for (int off = 32; off > 0; off >>= 1) {
    s1 += __shfl_down(s1, off);
    s2 += __shfl_down(s2, off);
  }
  __shared__ float r1[4], r2[4];
  if ((t & 63) == 0) { r1[t >> 6] = s1; r2[t >> 6] = s2; }
  __syncthreads();
  if (t == 0)
    stats[o] = make_float2((r1[0] + r1[1] + r1[2] + r1[3]) * (1.0f / IC),
                           (r2[0] + r2[1] + r2[2] + r2[3]) * (1.0f / IC));
}

__global__ __launch_bounds__(256) void gemv_kernel_fb(
    const float* __restrict__ x, const float* __restrict__ w,
    const int* __restrict__ mask, const float2* __restrict__ stats,
    float* __restrict__ part) {
  const int bx = blockIdx.x;
  const int tile = bx >> 2;
  const int sk = bx & 3;
  const int t = threadIdx.x;
  const int wvid = t >> 6;
  const int lane = t & 63;
  const int il = lane & 15;
  const int bg = lane >> 4;
  const int row0 = tile * 32 + wvid * 8;
  const int i0 = sk * (IC / SKF);
  const float* wr0 = w + (size_t)row0 * IC;
  const int* mk0 = mask + (size_t)row0 * IC;
  const float* xb = x + (size_t)(bg * 8) * IC;

  float2 stv[8];
#pragma unroll
  for (int r = 0; r < 8; ++r) stv[r] = stats[row0 + r];
  float acc[8][8];
#pragma unroll
  for (int r = 0; r < 8; ++r)
#pragma unroll
    for (int j = 0; j < 8; ++j) acc[r][j] = 0.f;

  for (int s_ = 0; s_ < (IC / SKF) / 64; ++s_) {
    const int i = i0 + (s_ << 6) + (il << 2);
    float4 wf[8];
#pragma unroll
    for (int r = 0; r < 8; ++r) {
      wf[r] = *reinterpret_cast<const float4*>(wr0 + (size_t)r * IC + i);
      const int4 mv = *reinterpret_cast<const int4*>(mk0 + (size_t)r * IC + i);
      const float m = stv[r].x, sc = stv[r].y;
      wf[r].x = mv.x ? wf[r].x : copysignf(sc, wf[r].x - m);
      wf[r].y = mv.y ? wf[r].y : copysignf(sc, wf[r].y - m);
      wf[r].z = mv.z ? wf[r].z : copysignf(sc, wf[r].z - m);
      wf[r].w = mv.w ? wf[r].w : copysignf(sc, wf[r].w - m);
    }
#pragma unroll
    for (int j = 0; j < 8; ++j) {
      const float4 xv = *reinterpret_cast<const float4*>(xb + (size_t)j * IC + i);
#pragma unroll
      for (int r = 0; r < 8; ++r)
        acc[r][j] += wf[r].x * xv.x + wf[r].y * xv.y + wf[r].z * xv.z +
                     wf[r].w * xv.w;
    }
  }
#pragma unroll
  for (int off = 8; off >= 1; off >>= 1)
#pragma unroll
    for (int r = 0; r < 8; ++r)
#pragma unroll
      for (int j = 0; j < 8; ++j) acc[r][j] += __shfl_xor(acc[r][j], off);
  if (il == 0)
#pragma unroll
    for (int r = 0; r < 8; ++r)
#pragma unroll
      for (int j = 0; j < 8; ++j)
        part[(size_t)sk * (BATCH * OC) + (size_t)(bg * 8 + j) * OC +
             (row0 + r)] = acc[r][j];
}

// ---------------- launch ----------------
extern "C" void kernel_launch(void* const* d_in, const int* in_sizes, int n_in,
                              void* d_out, int out_size, void* d_ws,
                              size_t ws_size, hipStream_t stream) {
  const float* x = (const float*)d_in[0];
  const float* w = (const float*)d_in[1];
  const float* bias = (const float*)d_in[2];
  const int* mask = (const int*)d_in[3];
  float* out = (float*)d_out;

  const size_t weff_b = (size_t)OC * IC * 2;          // 90,177,536
  const size_t xbf_b = (size_t)BATCH * IC * 2;        // 262,144
  const size_t part_b = (size_t)SKM * BATCH * OC * 4; // 11,272,192

  if (ws_size >= weff_b + xbf_b + part_b) {
    unsigned short* weff = (unsigned short*)d_ws;
    unsigned short* xbf = (unsigned short*)((char*)d_ws + weff_b);
    float* part = (float*)((char*)d_ws + weff_b + xbf_b);

    fuse_kernel<<<BATCH + OC, 1024, 0, stream>>>(w, mask, x, weff, xbf);
    mfma_kernel<<<(OC / 64) * SKM, 256, 0, stream>>>(weff, xbf, part);
    reduce_kernel<<<(BATCH * OC + 255) / 256, 256, 0, stream>>>(part, bias, out,
                                                                SKM);
  } else {
    float2* stats = (float2*)d_ws;
    float* part = (float*)((char*)d_ws + (size_t)OC * sizeof(float2));
    stats_kernel_fb<<<OC, 256, 0, stream>>>(mask, w, stats);
    gemv_kernel_fb<<<(OC / 32) * SKF, 256, 0, stream>>>(x, w, mask, stats, part);
    reduce_kernel<<<(BATCH * OC + 255) / 256, 256, 0, stream>>>(part, bias, out,
                                                                SKF);
  }
}